// Round 1
// baseline (145.756 us; speedup 1.0000x reference)
//
#include <hip/hip_runtime.h>

// Problem constants (B, L, NSESS, S, H) = (16, 512, 4, 512, 512)
constexpr int B     = 16;
constexpr int L     = 512;
constexpr int NSESS = 4;
constexpr int S     = 512;
constexpr int H     = 512;
constexpr int HV    = H / 4;   // 128 float4 per row

// One block per (b, l). 128 threads: lane j handles float4 column j of all
// 5 gathered rows. Rows are 2 KB contiguous -> fully coalesced loads/stores.
__global__ __launch_bounds__(128)
void state_matrix_encoder_kernel(const float* __restrict__ sess_repre,
                                 const int*   __restrict__ stm,
                                 float*       __restrict__ out)
{
    const int bl = blockIdx.x;        // 0 .. B*L-1
    const int b  = bl >> 9;           // bl / L   (L = 512)
    const int j  = threadIdx.x;       // float4 column, 0..127

    // 5 indices for this (b, l); same for all threads (scalar-broadcast loads)
    const int* stm_bl = stm + bl * 5;
    const int p0 = stm_bl[0] - 1;     // session 3
    const int p1 = stm_bl[1] - 1;     // session 0
    const int p2 = stm_bl[2] - 1;     // session 1
    const int p3 = stm_bl[3] - 1;     // session 2
    const int p4 = stm_bl[4] - 1;     // session 3

    const float4* base = (const float4*)sess_repre
                       + (size_t)b * (size_t)(NSESS * S * HV);

    const float4 v0 = base[(size_t)(3 * S + p0) * HV + j];
    const float4 v1 = base[(size_t)(0 * S + p1) * HV + j];
    const float4 v2 = base[(size_t)(1 * S + p2) * HV + j];
    const float4 v3 = base[(size_t)(2 * S + p3) * HV + j];
    const float4 v4 = base[(size_t)(3 * S + p4) * HV + j];

    float4 m;
    m.x = (v0.x + v1.x + v2.x + v3.x) * 0.25f;
    m.y = (v0.y + v1.y + v2.y + v3.y) * 0.25f;
    m.z = (v0.z + v1.z + v2.z + v3.z) * 0.25f;
    m.w = (v0.w + v1.w + v2.w + v3.w) * 0.25f;

    float4* o = (float4*)out + (size_t)bl * (size_t)(5 * HV) + j;
    o[0 * HV] = m;
    o[1 * HV] = v1;
    o[2 * HV] = v2;
    o[3 * HV] = v3;
    o[4 * HV] = v4;
}

extern "C" void kernel_launch(void* const* d_in, const int* in_sizes, int n_in,
                              void* d_out, int out_size, void* d_ws, size_t ws_size,
                              hipStream_t stream)
{
    // Input order (setup_inputs dict order):
    //   0: utterance_repre    (B, L, H)        float32  -- unused
    //   1: conversation_repre (B, H)           float32  -- unused
    //   2: session_repre      (B, NSESS, S, H) float32
    //   3: state_transition_matrix (B, L, 5)   int (harness stages ints as int32)
    //   4: max_conversation_length scalar      int      -- == L, unused
    const float* sess_repre = (const float*)d_in[2];
    const int*   stm        = (const int*)d_in[3];
    float*       out        = (float*)d_out;

    dim3 grid(B * L);   // 8192 blocks
    dim3 block(HV);     // 128 threads
    state_matrix_encoder_kernel<<<grid, block, 0, stream>>>(sess_repre, stm, out);
}